// Round 9
// baseline (129.578 us; speedup 1.0000x reference)
//
#include <hip/hip_runtime.h>

typedef unsigned short u16;
typedef __attribute__((ext_vector_type(8))) __bf16 bf16x8;
typedef __attribute__((ext_vector_type(4))) float f32x4;

#define GLD_LDS(src, dst) \
  __builtin_amdgcn_global_load_lds((const __attribute__((address_space(1))) void*)(src), \
                                   (__attribute__((address_space(3))) void*)(dst), 16, 0, 0)

__device__ __forceinline__ u16 f2bf(float f) {
  union { float f; unsigned int u; } c; c.f = f;
  unsigned int u = c.u + 0x7FFFu + ((c.u >> 16) & 1u);
  return (u16)(u >> 16);
}

__device__ __forceinline__ unsigned int cvt_pk_bf16(float lo, float hi) {
  unsigned int r;
  asm("v_cvt_pk_bf16_f32 %0, %1, %2" : "=v"(r) : "v"(lo), "v"(hi));
  return r;
}

// ---------------- LayerNorm: x fp32 [4096][1024] -> xn bf16 ----------------
__global__ __launch_bounds__(256) void ln_kernel(const float* __restrict__ x,
    const float* __restrict__ gamma, const float* __restrict__ beta,
    u16* __restrict__ xn)
{
  const int row = blockIdx.x, tid = threadIdx.x;
  const int lane = tid & 63, wave = tid >> 6;
  const float4 v = ((const float4*)(x + (size_t)row * 1024))[tid];
  float s = v.x + v.y + v.z + v.w;
  float q = v.x*v.x + v.y*v.y + v.z*v.z + v.w*v.w;
  #pragma unroll
  for (int m = 1; m < 64; m <<= 1) { s += __shfl_xor(s, m, 64); q += __shfl_xor(q, m, 64); }
  __shared__ float red[8];
  if (lane == 0) { red[wave] = s; red[4 + wave] = q; }
  __syncthreads();
  s = red[0] + red[1] + red[2] + red[3];
  q = red[4] + red[5] + red[6] + red[7];
  const float mu = s * (1.0f/1024.0f);
  const float var = q * (1.0f/1024.0f) - mu*mu;
  const float rs = rsqrtf(var + 1e-5f);
  const float4 gm = ((const float4*)gamma)[tid];
  const float4 bt = ((const float4*)beta)[tid];
  unsigned int w0 = (unsigned int)f2bf((v.x - mu)*rs*gm.x + bt.x)
                  | ((unsigned int)f2bf((v.y - mu)*rs*gm.y + bt.y) << 16);
  unsigned int w1 = (unsigned int)f2bf((v.z - mu)*rs*gm.z + bt.z)
                  | ((unsigned int)f2bf((v.w - mu)*rs*gm.w + bt.w) << 16);
  uint2 o; o.x = w0; o.y = w1;
  ((uint2*)(xn + (size_t)row * 1024))[tid] = o;
}

// ------- transpose+cast: in fp32 [K][N] -> out bf16 [N][K] -------
// rows n<scaleLim scaled by 0.125*log2(e) (QK^T lands in log2 domain -> exp2 softmax)
__global__ void transpose_cvt(const float* __restrict__ in, u16* __restrict__ out,
                              int K, int N, int scaleLim)
{
  __shared__ float t[32][33];
  const int n0 = blockIdx.x * 32, k0 = blockIdx.y * 32;
  const int lx = threadIdx.x, ly = threadIdx.y; // 32x8
  #pragma unroll
  for (int i = 0; i < 32; i += 8)
    t[ly + i][lx] = in[(size_t)(k0 + ly + i) * N + n0 + lx];
  __syncthreads();
  #pragma unroll
  for (int i = 0; i < 32; i += 8) {
    int n = n0 + ly + i;
    float v = t[lx][ly + i];
    if (n < scaleLim) v *= 0.18033688011116011f;   // 0.125 * log2(e)
    out[(size_t)n * K + k0 + lx] = f2bf(v);
  }
}

// ------- V transpose: qkv bf16 [4096][3072] (V cols) -> vt [32 bh][64 d][2048 n'] -------
// Key positions sigma-permuted within each 64-block (bit perm: p4=n3, p3=n2, p2=n4)
// so that attn's P^T B-fragment is exactly the lane-local cvt_pk-packed S registers.
__device__ __forceinline__ int vpos(int n) {
  return (n & ~63) | (n & 0x23) | ((n & 0x0C) << 1) | ((n & 0x10) >> 2);
}

__global__ __launch_bounds__(256) void vt_kernel(const u16* __restrict__ qkv,
                                                 u16* __restrict__ vt)
{
  const int bh = blockIdx.y, b = bh >> 4, h = bh & 15;
  const int d = threadIdx.x & 63, n8 = threadIdx.x >> 6;
  const int n = blockIdx.x * 32 + n8 * 8;
  const u16* src = qkv + (size_t)(b * 2048 + n) * 3072 + 2048 + h * 64 + d;
  unsigned int w[4];
  #pragma unroll
  for (int p = 0; p < 4; ++p) {
    unsigned int lo = src[(size_t)(2*p) * 3072];
    unsigned int hi = src[(size_t)(2*p + 1) * 3072];
    w[p] = lo | (hi << 16);
  }
  u16* dst = vt + ((size_t)bh * 64 + d) * 2048;
  uint2 o0; o0.x = w[0]; o0.y = w[1];
  uint2 o1; o1.x = w[2]; o1.y = w[3];
  *(uint2*)&dst[vpos(n)] = o0;       // keys n..n+3
  *(uint2*)&dst[vpos(n + 4)] = o1;   // keys n+4..n+7
}

// ---------------- GEMM: C[M][N] = A[M][K] * BT[N][K]^T, bf16 in, fp32 acc ----------------
// v9: double-buffered LDS (T3-minimum 2-phase): stage tile t+1 while computing tile t,
// ONE barrier per iter (the end-of-iter __syncthreads drains vmcnt before s_barrier,
// so next iter's reads of the just-staged buffer are safe). Mirrors the attn-v6-verified
// skeleton. LDS 64KB -> 2 blocks/CU.
template<bool FINAL>
__global__ __launch_bounds__(256, 2) void gemm_bt(
    const u16* __restrict__ A, const u16* __restrict__ BT,
    u16* __restrict__ outB, float* __restrict__ outF,
    const float* __restrict__ bias, int M, int N, int K)
{
  __shared__ __align__(16) u16 Alds[2][128 * 64];
  __shared__ __align__(16) u16 Blds[2][128 * 64];
  const int tid = threadIdx.x, wave = tid >> 6, lane = tid & 63;
  const int r15 = lane & 15, g = lane >> 4, l8 = lane >> 3, c8 = lane & 7;
  const int row0 = blockIdx.y * 128, col0 = blockIdx.x * 128;
  const int wm = (wave >> 1) * 64, wn = (wave & 1) * 64;
  const int srcCol = (c8 ^ l8) << 3;

  f32x4 acc[4][4] = {};
  const int NT = K >> 6;

  // prologue: stage tile 0
  #pragma unroll
  for (int c = 0; c < 4; ++c) {
    const int r0 = wave * 32 + c * 8;
    GLD_LDS(A  + (size_t)(row0 + r0 + l8) * K + srcCol, &Alds[0][r0 * 64]);
    GLD_LDS(BT + (size_t)(col0 + r0 + l8) * K + srcCol, &Blds[0][r0 * 64]);
  }
  __syncthreads();

  for (int t = 0; t < NT; ++t) {
    const int cur = t & 1;
    if (t < NT - 1) {
      const int nxt = cur ^ 1, kn = (t + 1) << 6;
      #pragma unroll
      for (int c = 0; c < 4; ++c) {
        const int r0 = wave * 32 + c * 8;
        GLD_LDS(A  + (size_t)(row0 + r0 + l8) * K + kn + srcCol, &Alds[nxt][r0 * 64]);
        GLD_LDS(BT + (size_t)(col0 + r0 + l8) * K + kn + srcCol, &Blds[nxt][r0 * 64]);
      }
    }
    const char* abase = (const char*)&Alds[cur][0];
    const char* bbase = (const char*)&Blds[cur][0];
    #pragma unroll
    for (int kk = 0; kk < 2; ++kk) {
      bf16x8 af[4], bf[4];
      #pragma unroll
      for (int m = 0; m < 4; ++m) {
        int row = wm + m * 16 + r15;
        af[m] = *(const bf16x8*)(abase + row * 128 + ((kk*64 + g*16) ^ ((row & 7) << 4)));
        row = wn + m * 16 + r15;
        bf[m] = *(const bf16x8*)(bbase + row * 128 + ((kk*64 + g*16) ^ ((row & 7) << 4)));
      }
      #pragma unroll
      for (int m = 0; m < 4; ++m)
        #pragma unroll
        for (int n = 0; n < 4; ++n)
          acc[m][n] = __builtin_amdgcn_mfma_f32_16x16x32_bf16(af[m], bf[n], acc[m][n], 0, 0, 0);
    }
    __syncthreads();
  }

  #pragma unroll
  for (int m = 0; m < 4; ++m)
    #pragma unroll
    for (int n = 0; n < 4; ++n) {
      const int row = row0 + wm + m * 16 + g * 4;
      const int col = col0 + wn + n * 16 + r15;
      if constexpr (FINAL) {
        const float bv = bias[col];
        #pragma unroll
        for (int r = 0; r < 4; ++r)
          outF[(size_t)(row + r) * N + col] = acc[m][n][r] + bv;
      } else {
        #pragma unroll
        for (int r = 0; r < 4; ++r)
          outB[(size_t)(row + r) * N + col] = f2bf(acc[m][n][r]);
      }
    }
}

// ---------------- Flash attention v6 (verified r6: 48.5us, absmax 2e-3) ----------------
// no-max exp2 softmax (log2-domain scores, |S|<~10), sigma-permuted V -> zero-relayout P,
// dbuf K/V, 1 barrier/iter, l-sum on the matrix pipe via ones-A MFMA.
__global__ __launch_bounds__(256, 4) void attn_kernel(const u16* __restrict__ qkv,
                                                      const u16* __restrict__ vt,
                                                      u16* __restrict__ attnO)
{
  __shared__ __align__(16) u16 Klds[2][64 * 64];   // [key][d], XOR-swizzled rows
  __shared__ __align__(16) u16 Vlds[2][64 * 64];   // [d][key'], XOR-swizzled rows

  const int tid = threadIdx.x, wave = tid >> 6, lane = tid & 63;
  const int r15 = lane & 15, g = lane >> 4, l8 = lane >> 3, c8 = lane & 7;
  const int bh = blockIdx.x, qt = blockIdx.y;
  const int b = bh >> 4, h = bh & 15;

  const u16* Qp = qkv + (size_t)b * 2048 * 3072 + h * 64;
  const u16* Kp = Qp + 1024;
  const u16* Vt = vt + (size_t)bh * 64 * 2048;

  const int q0 = qt * 64 + wave * 16;

  // Q fragments (B operand of QK): lane r15 = q-row
  bf16x8 qf[2];
  #pragma unroll
  for (int kk = 0; kk < 2; ++kk)
    qf[kk] = *(const bf16x8*)(Qp + (size_t)(q0 + r15) * 3072 + kk*32 + g*8);

  f32x4 acc[4] = {};   // acc[nf]: q = r15, d = nf*16 + g*4 + r
  f32x4 accl = {};     // l for q-row r15 (all 4 regs identical; ones-A MFMA)

  const int srcCol = (c8 ^ l8) << 3;

  // ones A-fragment for the l-sum MFMA
  const unsigned int one2 = 0x3F803F80u;
  uint4 onesu; onesu.x = one2; onesu.y = one2; onesu.z = one2; onesu.w = one2;
  const bf16x8 onesf = *(const bf16x8*)&onesu;

  // invariant LDS fragment byte offsets (8 VGPRs); (row&7)==(r15&7) since row=m*16+r15
  int offp[2][4];
  #pragma unroll
  for (int kk = 0; kk < 2; ++kk)
    #pragma unroll
    for (int m = 0; m < 4; ++m)
      offp[kk][m] = (m * 16 + r15) * 128 + ((kk * 64 + g * 16) ^ ((r15 & 7) << 4));

  // prologue: stage tile 0
  #pragma unroll
  for (int c = 0; c < 2; ++c) {
    const int r0 = wave * 16 + c * 8;
    GLD_LDS(Kp + (size_t)(r0 + l8) * 3072 + srcCol, &Klds[0][r0 * 64]);
    GLD_LDS(Vt + (size_t)(r0 + l8) * 2048 + srcCol, &Vlds[0][r0 * 64]);
  }
  __syncthreads();

  #pragma unroll 2
  for (int kt = 0; kt < 32; ++kt) {
    const int cur = kt & 1;
    if (kt < 31) {
      const int nxt = cur ^ 1, kn = kt + 1;
      #pragma unroll
      for (int c = 0; c < 2; ++c) {
        const int r0 = wave * 16 + c * 8;
        GLD_LDS(Kp + (size_t)(kn*64 + r0 + l8) * 3072 + srcCol, &Klds[nxt][r0 * 64]);
        GLD_LDS(Vt + (size_t)(r0 + l8) * 2048 + kn*64 + srcCol, &Vlds[nxt][r0 * 64]);
      }
    }

    // S^T = K x Q: s[m][r] = score(q=r15, key = m*16 + g*4 + r), log2 domain
    const char* kbase = (const char*)&Klds[cur][0];
    bf16x8 kf[2][4];
    #pragma unroll
    for (int kk = 0; kk < 2; ++kk)
      #pragma unroll
      for (int m = 0; m < 4; ++m)
        kf[kk][m] = *(const bf16x8*)(kbase + offp[kk][m]);
    f32x4 s[4] = {};
    #pragma unroll
    for (int kk = 0; kk < 2; ++kk)
      #pragma unroll
      for (int m = 0; m < 4; ++m)
        s[m] = __builtin_amdgcn_mfma_f32_16x16x32_bf16(kf[kk][m], qf[kk], s[m], 0, 0, 0);

    // P = exp2(S), unnormalized (no max, no rescale — see header comment)
    #pragma unroll
    for (int m = 0; m < 4; ++m)
      #pragma unroll
      for (int r = 0; r < 4; ++r)
        s[m][r] = __builtin_amdgcn_exp2f(s[m][r]);

    // pack P: B-frag of P^T = lane-local packed words in order (sigma-permuted V)
    unsigned int u[4][2];
    #pragma unroll
    for (int m = 0; m < 4; ++m) {
      u[m][0] = cvt_pk_bf16(s[m][0], s[m][1]);
      u[m][1] = cvt_pk_bf16(s[m][2], s[m][3]);
    }
    uint4 pw[2];
    pw[0].x = u[0][0]; pw[0].y = u[0][1]; pw[0].z = u[1][0]; pw[0].w = u[1][1];
    pw[1].x = u[2][0]; pw[1].y = u[2][1]; pw[1].z = u[3][0]; pw[1].w = u[3][1];

    // O^T += V^T x P^T ; l += ones x P^T (matrix pipe)
    const char* vbase = (const char*)&Vlds[cur][0];
    bf16x8 vf[2][4];
    #pragma unroll
    for (int kk = 0; kk < 2; ++kk)
      #pragma unroll
      for (int nf = 0; nf < 4; ++nf)
        vf[kk][nf] = *(const bf16x8*)(vbase + offp[kk][nf]);
    #pragma unroll
    for (int kk = 0; kk < 2; ++kk) {
      const bf16x8 pfk = *(const bf16x8*)&pw[kk];
      accl = __builtin_amdgcn_mfma_f32_16x16x32_bf16(onesf, pfk, accl, 0, 0, 0);
      #pragma unroll
      for (int nf = 0; nf < 4; ++nf)
        acc[nf] = __builtin_amdgcn_mfma_f32_16x16x32_bf16(vf[kk][nf], pfk, acc[nf], 0, 0, 0);
    }

    __syncthreads();
  }

  // epilogue: normalize by lane-local l (accl regs all equal) and store 8B per nf
  const float linv = 1.0f / accl[0];
  const size_t base = (size_t)(b * 2048 + q0 + r15) * 1024 + h * 64;
  #pragma unroll
  for (int nf = 0; nf < 4; ++nf) {
    uint2 o;
    o.x = cvt_pk_bf16(acc[nf][0] * linv, acc[nf][1] * linv);
    o.y = cvt_pk_bf16(acc[nf][2] * linv, acc[nf][3] * linv);
    *(uint2*)&attnO[base + nf*16 + g*4] = o;
  }
}

// ---------------------------------------------------------------------------
extern "C" void kernel_launch(void* const* d_in, const int* in_sizes, int n_in,
                              void* d_out, int out_size, void* d_ws, size_t ws_size,
                              hipStream_t stream) {
  const float* x     = (const float*)d_in[0];
  const float* gamma = (const float*)d_in[1];
  const float* beta  = (const float*)d_in[2];
  const float* w_qkv = (const float*)d_in[3];
  const float* w_out = (const float*)d_in[4];
  const float* b_out = (const float*)d_in[5];
  float* out = (float*)d_out;
  char* ws = (char*)d_ws;

  u16* xn    = (u16*)(ws);                     //  8 MB: [4096][1024] (dead after gemm1)
  u16* vtbuf = (u16*)(ws);                     //  8 MB: vt aliases xn
  u16* wqkvT = (u16*)(ws + ( 8u << 20));       //  6 MB: [3072][1024] (q rows pre-scaled 0.125*log2e)
  u16* qkv   = (u16*)(ws + (14u << 20));       // 24 MB: [4096][3072]
  u16* woutT = (u16*)(ws + (38u << 20));       //  2 MB: [1024][1024]
  u16* attnO = (u16*)(ws + (40u << 20));       //  8 MB: [4096][1024]

  ln_kernel<<<4096, 256, 0, stream>>>(x, gamma, beta, xn);
  transpose_cvt<<<dim3(96, 32), dim3(32, 8), 0, stream>>>(w_qkv, wqkvT, 1024, 3072, 1024);
  transpose_cvt<<<dim3(32, 32), dim3(32, 8), 0, stream>>>(w_out, woutT, 1024, 1024, 0);
  gemm_bt<false><<<dim3(24, 32), 256, 0, stream>>>(xn, wqkvT, qkv, nullptr, nullptr, 4096, 3072, 1024);
  vt_kernel<<<dim3(64, 32), 256, 0, stream>>>(qkv, vtbuf);
  attn_kernel<<<dim3(32, 32), 256, 0, stream>>>(qkv, vtbuf, attnO);
  gemm_bt<true><<<dim3(8, 32), 256, 0, stream>>>(attnO, woutT, nullptr, out, b_out, 4096, 1024, 1024);
}

// Round 10
// 118.964 us; speedup vs baseline: 1.0892x; 1.0892x over previous
//
#include <hip/hip_runtime.h>

typedef unsigned short u16;
typedef __attribute__((ext_vector_type(8))) __bf16 bf16x8;
typedef __attribute__((ext_vector_type(4))) float f32x4;

#define GLD_LDS(src, dst) \
  __builtin_amdgcn_global_load_lds((const __attribute__((address_space(1))) void*)(src), \
                                   (__attribute__((address_space(3))) void*)(dst), 16, 0, 0)

__device__ __forceinline__ u16 f2bf(float f) {
  union { float f; unsigned int u; } c; c.f = f;
  unsigned int u = c.u + 0x7FFFu + ((c.u >> 16) & 1u);
  return (u16)(u >> 16);
}

__device__ __forceinline__ unsigned int cvt_pk_bf16(float lo, float hi) {
  unsigned int r;
  asm("v_cvt_pk_bf16_f32 %0, %1, %2" : "=v"(r) : "v"(lo), "v"(hi));
  return r;
}

// ---------------- LayerNorm: x fp32 [4096][1024] -> xn bf16 ----------------
__global__ __launch_bounds__(256) void ln_kernel(const float* __restrict__ x,
    const float* __restrict__ gamma, const float* __restrict__ beta,
    u16* __restrict__ xn)
{
  const int row = blockIdx.x, tid = threadIdx.x;
  const int lane = tid & 63, wave = tid >> 6;
  const float4 v = ((const float4*)(x + (size_t)row * 1024))[tid];
  float s = v.x + v.y + v.z + v.w;
  float q = v.x*v.x + v.y*v.y + v.z*v.z + v.w*v.w;
  #pragma unroll
  for (int m = 1; m < 64; m <<= 1) { s += __shfl_xor(s, m, 64); q += __shfl_xor(q, m, 64); }
  __shared__ float red[8];
  if (lane == 0) { red[wave] = s; red[4 + wave] = q; }
  __syncthreads();
  s = red[0] + red[1] + red[2] + red[3];
  q = red[4] + red[5] + red[6] + red[7];
  const float mu = s * (1.0f/1024.0f);
  const float var = q * (1.0f/1024.0f) - mu*mu;
  const float rs = rsqrtf(var + 1e-5f);
  const float4 gm = ((const float4*)gamma)[tid];
  const float4 bt = ((const float4*)beta)[tid];
  unsigned int w0 = (unsigned int)f2bf((v.x - mu)*rs*gm.x + bt.x)
                  | ((unsigned int)f2bf((v.y - mu)*rs*gm.y + bt.y) << 16);
  unsigned int w1 = (unsigned int)f2bf((v.z - mu)*rs*gm.z + bt.z)
                  | ((unsigned int)f2bf((v.w - mu)*rs*gm.w + bt.w) << 16);
  uint2 o; o.x = w0; o.y = w1;
  ((uint2*)(xn + (size_t)row * 1024))[tid] = o;
}

// ------- transpose+cast: in fp32 [K][N] -> out bf16 [N][K] -------
// rows n<scaleLim scaled by 0.125*log2(e) (QK^T lands in log2 domain -> exp2 softmax)
__global__ void transpose_cvt(const float* __restrict__ in, u16* __restrict__ out,
                              int K, int N, int scaleLim)
{
  __shared__ float t[32][33];
  const int n0 = blockIdx.x * 32, k0 = blockIdx.y * 32;
  const int lx = threadIdx.x, ly = threadIdx.y; // 32x8
  #pragma unroll
  for (int i = 0; i < 32; i += 8)
    t[ly + i][lx] = in[(size_t)(k0 + ly + i) * N + n0 + lx];
  __syncthreads();
  #pragma unroll
  for (int i = 0; i < 32; i += 8) {
    int n = n0 + ly + i;
    float v = t[lx][ly + i];
    if (n < scaleLim) v *= 0.18033688011116011f;   // 0.125 * log2(e)
    out[(size_t)n * K + k0 + lx] = f2bf(v);
  }
}

// ------- V transpose: qkv bf16 [4096][3072] (V cols) -> vt [32 bh][64 d][2048 n'] -------
// Key positions sigma-permuted within each 64-block (bit perm: p4=n3, p3=n2, p2=n4)
// so that attn's P^T B-fragment is exactly the lane-local cvt_pk-packed S registers.
__device__ __forceinline__ int vpos(int n) {
  return (n & ~63) | (n & 0x23) | ((n & 0x0C) << 1) | ((n & 0x10) >> 2);
}

__global__ __launch_bounds__(256) void vt_kernel(const u16* __restrict__ qkv,
                                                 u16* __restrict__ vt)
{
  const int bh = blockIdx.y, b = bh >> 4, h = bh & 15;
  const int d = threadIdx.x & 63, n8 = threadIdx.x >> 6;
  const int n = blockIdx.x * 32 + n8 * 8;
  const u16* src = qkv + (size_t)(b * 2048 + n) * 3072 + 2048 + h * 64 + d;
  unsigned int w[4];
  #pragma unroll
  for (int p = 0; p < 4; ++p) {
    unsigned int lo = src[(size_t)(2*p) * 3072];
    unsigned int hi = src[(size_t)(2*p + 1) * 3072];
    w[p] = lo | (hi << 16);
  }
  u16* dst = vt + ((size_t)bh * 64 + d) * 2048;
  uint2 o0; o0.x = w[0]; o0.y = w[1];
  uint2 o1; o1.x = w[2]; o1.y = w[3];
  *(uint2*)&dst[vpos(n)] = o0;       // keys n..n+3
  *(uint2*)&dst[vpos(n + 4)] = o1;   // keys n+4..n+7
}

// ---------------- GEMM: C[M][N] = A[M][K] * BT[N][K]^T, bf16 in, fp32 acc ----------------
// r6-verified single-buffer structure (32KB LDS -> 5 blocks/CU) + T1 XCD-aware block
// swizzle: XCD k (hardware id lin%8) gets the contiguous logical chunk [k*cpx,(k+1)*cpx)
// -> A-panel reuse lands in the XCD's private L2. Requires nwg%8==0 (768 and 256: yes).
template<bool FINAL>
__global__ __launch_bounds__(256, 2) void gemm_bt(
    const u16* __restrict__ A, const u16* __restrict__ BT,
    u16* __restrict__ outB, float* __restrict__ outF,
    const float* __restrict__ bias, int M, int N, int K)
{
  __shared__ __align__(16) u16 Alds[128 * 64];
  __shared__ __align__(16) u16 Blds[128 * 64];
  const int tid = threadIdx.x, wave = tid >> 6, lane = tid & 63;
  const int r15 = lane & 15, g = lane >> 4, l8 = lane >> 3, c8 = lane & 7;

  // XCD swizzle (bijective: nwg % 8 == 0)
  const int nwgx = gridDim.x;
  const int lin = blockIdx.x + blockIdx.y * nwgx;
  const int cpx = (nwgx * gridDim.y) >> 3;
  const int swz = (lin & 7) * cpx + (lin >> 3);
  const int row0 = (swz / nwgx) * 128, col0 = (swz % nwgx) * 128;

  const int wm = (wave >> 1) * 64, wn = (wave & 1) * 64;
  const int srcCol = (c8 ^ l8) << 3;

  f32x4 acc[4][4] = {};

  for (int kt = 0; kt < K; kt += 64) {
    #pragma unroll
    for (int c = 0; c < 4; ++c) {
      const int r0 = wave * 32 + c * 8;
      GLD_LDS(A  + (size_t)(row0 + r0 + l8) * K + kt + srcCol, Alds + r0 * 64);
      GLD_LDS(BT + (size_t)(col0 + r0 + l8) * K + kt + srcCol, Blds + r0 * 64);
    }
    __syncthreads();
    #pragma unroll
    for (int kk = 0; kk < 2; ++kk) {
      bf16x8 af[4], bf[4];
      #pragma unroll
      for (int m = 0; m < 4; ++m) {
        int row = wm + m * 16 + r15;
        af[m] = *(const bf16x8*)((const char*)Alds + row * 128 + ((kk*64 + g*16) ^ ((row & 7) << 4)));
        row = wn + m * 16 + r15;
        bf[m] = *(const bf16x8*)((const char*)Blds + row * 128 + ((kk*64 + g*16) ^ ((row & 7) << 4)));
      }
      #pragma unroll
      for (int m = 0; m < 4; ++m)
        #pragma unroll
        for (int n = 0; n < 4; ++n)
          acc[m][n] = __builtin_amdgcn_mfma_f32_16x16x32_bf16(af[m], bf[n], acc[m][n], 0, 0, 0);
    }
    __syncthreads();
  }

  #pragma unroll
  for (int m = 0; m < 4; ++m)
    #pragma unroll
    for (int n = 0; n < 4; ++n) {
      const int row = row0 + wm + m * 16 + g * 4;
      const int col = col0 + wn + n * 16 + r15;
      if constexpr (FINAL) {
        const float bv = bias[col];
        #pragma unroll
        for (int r = 0; r < 4; ++r)
          outF[(size_t)(row + r) * N + col] = acc[m][n][r] + bv;
      } else {
        #pragma unroll
        for (int r = 0; r < 4; ++r)
          outB[(size_t)(row + r) * N + col] = f2bf(acc[m][n][r]);
      }
    }
}

// ---------------- Flash attention v6 (verified r6/r9: 48.5us, absmax 2e-3) ----------------
// no-max exp2 softmax (log2-domain scores, |S|<~10), sigma-permuted V -> zero-relayout P,
// dbuf K/V, 1 barrier/iter, l-sum on the matrix pipe via ones-A MFMA.
__global__ __launch_bounds__(256, 4) void attn_kernel(const u16* __restrict__ qkv,
                                                      const u16* __restrict__ vt,
                                                      u16* __restrict__ attnO)
{
  __shared__ __align__(16) u16 Klds[2][64 * 64];   // [key][d], XOR-swizzled rows
  __shared__ __align__(16) u16 Vlds[2][64 * 64];   // [d][key'], XOR-swizzled rows

  const int tid = threadIdx.x, wave = tid >> 6, lane = tid & 63;
  const int r15 = lane & 15, g = lane >> 4, l8 = lane >> 3, c8 = lane & 7;
  const int bh = blockIdx.x, qt = blockIdx.y;
  const int b = bh >> 4, h = bh & 15;

  const u16* Qp = qkv + (size_t)b * 2048 * 3072 + h * 64;
  const u16* Kp = Qp + 1024;
  const u16* Vt = vt + (size_t)bh * 64 * 2048;

  const int q0 = qt * 64 + wave * 16;

  // Q fragments (B operand of QK): lane r15 = q-row
  bf16x8 qf[2];
  #pragma unroll
  for (int kk = 0; kk < 2; ++kk)
    qf[kk] = *(const bf16x8*)(Qp + (size_t)(q0 + r15) * 3072 + kk*32 + g*8);

  f32x4 acc[4] = {};   // acc[nf]: q = r15, d = nf*16 + g*4 + r
  f32x4 accl = {};     // l for q-row r15 (all 4 regs identical; ones-A MFMA)

  const int srcCol = (c8 ^ l8) << 3;

  // ones A-fragment for the l-sum MFMA
  const unsigned int one2 = 0x3F803F80u;
  uint4 onesu; onesu.x = one2; onesu.y = one2; onesu.z = one2; onesu.w = one2;
  const bf16x8 onesf = *(const bf16x8*)&onesu;

  // invariant LDS fragment byte offsets (8 VGPRs); (row&7)==(r15&7) since row=m*16+r15
  int offp[2][4];
  #pragma unroll
  for (int kk = 0; kk < 2; ++kk)
    #pragma unroll
    for (int m = 0; m < 4; ++m)
      offp[kk][m] = (m * 16 + r15) * 128 + ((kk * 64 + g * 16) ^ ((r15 & 7) << 4));

  // prologue: stage tile 0
  #pragma unroll
  for (int c = 0; c < 2; ++c) {
    const int r0 = wave * 16 + c * 8;
    GLD_LDS(Kp + (size_t)(r0 + l8) * 3072 + srcCol, &Klds[0][r0 * 64]);
    GLD_LDS(Vt + (size_t)(r0 + l8) * 2048 + srcCol, &Vlds[0][r0 * 64]);
  }
  __syncthreads();

  #pragma unroll 2
  for (int kt = 0; kt < 32; ++kt) {
    const int cur = kt & 1;
    if (kt < 31) {
      const int nxt = cur ^ 1, kn = kt + 1;
      #pragma unroll
      for (int c = 0; c < 2; ++c) {
        const int r0 = wave * 16 + c * 8;
        GLD_LDS(Kp + (size_t)(kn*64 + r0 + l8) * 3072 + srcCol, &Klds[nxt][r0 * 64]);
        GLD_LDS(Vt + (size_t)(r0 + l8) * 2048 + kn*64 + srcCol, &Vlds[nxt][r0 * 64]);
      }
    }

    // S^T = K x Q: s[m][r] = score(q=r15, key = m*16 + g*4 + r), log2 domain
    const char* kbase = (const char*)&Klds[cur][0];
    bf16x8 kf[2][4];
    #pragma unroll
    for (int kk = 0; kk < 2; ++kk)
      #pragma unroll
      for (int m = 0; m < 4; ++m)
        kf[kk][m] = *(const bf16x8*)(kbase + offp[kk][m]);
    f32x4 s[4] = {};
    #pragma unroll
    for (int kk = 0; kk < 2; ++kk)
      #pragma unroll
      for (int m = 0; m < 4; ++m)
        s[m] = __builtin_amdgcn_mfma_f32_16x16x32_bf16(kf[kk][m], qf[kk], s[m], 0, 0, 0);

    // P = exp2(S), unnormalized (no max, no rescale — see header comment)
    #pragma unroll
    for (int m = 0; m < 4; ++m)
      #pragma unroll
      for (int r = 0; r < 4; ++r)
        s[m][r] = __builtin_amdgcn_exp2f(s[m][r]);

    // pack P: B-frag of P^T = lane-local packed words in order (sigma-permuted V)
    unsigned int u[4][2];
    #pragma unroll
    for (int m = 0; m < 4; ++m) {
      u[m][0] = cvt_pk_bf16(s[m][0], s[m][1]);
      u[m][1] = cvt_pk_bf16(s[m][2], s[m][3]);
    }
    uint4 pw[2];
    pw[0].x = u[0][0]; pw[0].y = u[0][1]; pw[0].z = u[1][0]; pw[0].w = u[1][1];
    pw[1].x = u[2][0]; pw[1].y = u[2][1]; pw[1].z = u[3][0]; pw[1].w = u[3][1];

    // O^T += V^T x P^T ; l += ones x P^T (matrix pipe)
    const char* vbase = (const char*)&Vlds[cur][0];
    bf16x8 vf[2][4];
    #pragma unroll
    for (int kk = 0; kk < 2; ++kk)
      #pragma unroll
      for (int nf = 0; nf < 4; ++nf)
        vf[kk][nf] = *(const bf16x8*)(vbase + offp[kk][nf]);
    #pragma unroll
    for (int kk = 0; kk < 2; ++kk) {
      const bf16x8 pfk = *(const bf16x8*)&pw[kk];
      accl = __builtin_amdgcn_mfma_f32_16x16x32_bf16(onesf, pfk, accl, 0, 0, 0);
      #pragma unroll
      for (int nf = 0; nf < 4; ++nf)
        acc[nf] = __builtin_amdgcn_mfma_f32_16x16x32_bf16(vf[kk][nf], pfk, acc[nf], 0, 0, 0);
    }

    __syncthreads();
  }

  // epilogue: normalize by lane-local l (accl regs all equal) and store 8B per nf
  const float linv = 1.0f / accl[0];
  const size_t base = (size_t)(b * 2048 + q0 + r15) * 1024 + h * 64;
  #pragma unroll
  for (int nf = 0; nf < 4; ++nf) {
    uint2 o;
    o.x = cvt_pk_bf16(acc[nf][0] * linv, acc[nf][1] * linv);
    o.y = cvt_pk_bf16(acc[nf][2] * linv, acc[nf][3] * linv);
    *(uint2*)&attnO[base + nf*16 + g*4] = o;
  }
}

// ---------------------------------------------------------------------------
extern "C" void kernel_launch(void* const* d_in, const int* in_sizes, int n_in,
                              void* d_out, int out_size, void* d_ws, size_t ws_size,
                              hipStream_t stream) {
  const float* x     = (const float*)d_in[0];
  const float* gamma = (const float*)d_in[1];
  const float* beta  = (const float*)d_in[2];
  const float* w_qkv = (const float*)d_in[3];
  const float* w_out = (const float*)d_in[4];
  const float* b_out = (const float*)d_in[5];
  float* out = (float*)d_out;
  char* ws = (char*)d_ws;

  u16* xn    = (u16*)(ws);                     //  8 MB: [4096][1024] (dead after gemm1)
  u16* vtbuf = (u16*)(ws);                     //  8 MB: vt aliases xn
  u16* wqkvT = (u16*)(ws + ( 8u << 20));       //  6 MB: [3072][1024] (q rows pre-scaled 0.125*log2e)
  u16* qkv   = (u16*)(ws + (14u << 20));       // 24 MB: [4096][3072]
  u16* woutT = (u16*)(ws + (38u << 20));       //  2 MB: [1024][1024]
  u16* attnO = (u16*)(ws + (40u << 20));       //  8 MB: [4096][1024]

  ln_kernel<<<4096, 256, 0, stream>>>(x, gamma, beta, xn);
  transpose_cvt<<<dim3(96, 32), dim3(32, 8), 0, stream>>>(w_qkv, wqkvT, 1024, 3072, 1024);
  transpose_cvt<<<dim3(32, 32), dim3(32, 8), 0, stream>>>(w_out, woutT, 1024, 1024, 0);
  gemm_bt<false><<<dim3(24, 32), 256, 0, stream>>>(xn, wqkvT, qkv, nullptr, nullptr, 4096, 3072, 1024);
  vt_kernel<<<dim3(64, 32), 256, 0, stream>>>(qkv, vtbuf);
  attn_kernel<<<dim3(32, 32), 256, 0, stream>>>(qkv, vtbuf, attnO);
  gemm_bt<true><<<dim3(8, 32), 256, 0, stream>>>(attnO, woutT, nullptr, out, b_out, 4096, 1024, 1024);
}